// Round 1
// baseline (49.116 us; speedup 1.0000x reference)
//
#include <hip/hip_runtime.h>

// QuantumLikeLayer: out[b,:] = CZ_diag * (H^{kron 11} @ x[b,:])
// H^{kron 11} is the natural-order Walsh-Hadamard transform scaled by 2^-5.5.
// Fast WHT: 11 radix-2 butterfly stages (one per index bit, order-free).
// CZ_diag[i] = -1 iff bits 10 and 9 of i are both 1.

#define N 2048
#define ROWS_PER_BLOCK 4  // 4 waves/block, one row per wave

__global__ __launch_bounds__(256) void QuantumLikeLayer_kernel(
    const float* __restrict__ in, float* __restrict__ out, int batch) {
    const int lane = threadIdx.x & 63;
    const int wave = threadIdx.x >> 6;
    const int row = blockIdx.x * ROWS_PER_BLOCK + wave;
    if (row >= batch) return;

    const float* src = in + (size_t)row * N;
    float*       dst = out + (size_t)row * N;

    // Element index i = r*256 + lane*4 + c  (r: bits 8-10, lane: bits 2-7, c: bits 0-1)
    float4 v[8];
#pragma unroll
    for (int r = 0; r < 8; ++r) {
        v[r] = *reinterpret_cast<const float4*>(src + r * 256 + lane * 4);
    }

    // --- stages over bits 0,1 (within float4) ---
#pragma unroll
    for (int r = 0; r < 8; ++r) {
        float4 a = v[r];
        float x = a.x + a.y, y = a.x - a.y;   // bit 0: (x,y),(z,w)
        float z = a.z + a.w, w = a.z - a.w;
        a.x = x + z; a.z = x - z;             // bit 1: (x,z),(y,w)
        a.y = y + w; a.w = y - w;
        v[r] = a;
    }

    // --- stages over bits 2..7 (lane bits), xor masks 1..32 ---
#pragma unroll
    for (int m = 1; m <= 32; m <<= 1) {
        const float s = (lane & m) ? -1.0f : 1.0f;
#pragma unroll
        for (int r = 0; r < 8; ++r) {
            float4 a = v[r];
            float px = __shfl_xor(a.x, m, 64);
            float py = __shfl_xor(a.y, m, 64);
            float pz = __shfl_xor(a.z, m, 64);
            float pw = __shfl_xor(a.w, m, 64);
            a.x = px + s * a.x;
            a.y = py + s * a.y;
            a.z = pz + s * a.z;
            a.w = pw + s * a.w;
            v[r] = a;
        }
    }

    // --- stages over bits 8,9,10 (r strides 1,2,4) ---
#pragma unroll
    for (int s = 1; s <= 4; s <<= 1) {
#pragma unroll
        for (int i = 0; i < 8; ++i) {
            if ((i & s) == 0) {
                float4 a = v[i], b = v[i + s];
                v[i].x = a.x + b.x; v[i].y = a.y + b.y;
                v[i].z = a.z + b.z; v[i].w = a.w + b.w;
                v[i + s].x = a.x - b.x; v[i + s].y = a.y - b.y;
                v[i + s].z = a.z - b.z; v[i + s].w = a.w - b.w;
            }
        }
    }

    // --- scale 1/sqrt(2048), CZ sign = -1 iff r bits 2,1 both set (r=6,7) ---
    const float SCALE = 0.022097086912079612f;  // 2^-5.5
#pragma unroll
    for (int r = 0; r < 8; ++r) {
        const float sc = ((r & 6) == 6) ? -SCALE : SCALE;
        float4 a = v[r];
        a.x *= sc; a.y *= sc; a.z *= sc; a.w *= sc;
        *reinterpret_cast<float4*>(dst + r * 256 + lane * 4) = a;
    }
}

extern "C" void kernel_launch(void* const* d_in, const int* in_sizes, int n_in,
                              void* d_out, int out_size, void* d_ws, size_t ws_size,
                              hipStream_t stream) {
    const float* in = (const float*)d_in[0];
    float* out = (float*)d_out;
    const int batch = in_sizes[0] / N;  // 16384
    const int grid = (batch + ROWS_PER_BLOCK - 1) / ROWS_PER_BLOCK;
    QuantumLikeLayer_kernel<<<grid, 256, 0, stream>>>(in, out, batch);
}

// Round 3
// 47.288 us; speedup vs baseline: 1.0387x; 1.0387x over previous
//
#include <hip/hip_runtime.h>

// QuantumLikeLayer: out[b,:] = CZ_diag * (H^{kron 11} @ x[b,:])
// H^{kron 11} is the natural-order Walsh-Hadamard transform scaled by 2^-5.5.
// Fast WHT: 11 radix-2 butterfly stages (one per index bit, order-free).
// CZ_diag[i] = -1 iff bits 10 and 9 of i are both 1.
//
// R3: non-temporal stores via native ext_vector type (HIP_vector_type<float,4>
// is rejected by __builtin_nontemporal_store). Output is write-once; nt keeps
// output lines from evicting the 128 MiB input out of the 256 MiB Infinity
// Cache across graph replays.

#define N 2048
#define ROWS_PER_BLOCK 4  // 4 waves/block, one row per wave

typedef float f32x4 __attribute__((ext_vector_type(4)));

__global__ __launch_bounds__(256) void QuantumLikeLayer_kernel(
    const float* __restrict__ in, float* __restrict__ out, int batch) {
    const int lane = threadIdx.x & 63;
    const int wave = threadIdx.x >> 6;
    const int row = blockIdx.x * ROWS_PER_BLOCK + wave;
    if (row >= batch) return;

    const float* src = in + (size_t)row * N;
    float*       dst = out + (size_t)row * N;

    // Element index i = r*256 + lane*4 + c  (r: bits 8-10, lane: bits 2-7, c: bits 0-1)
    float4 v[8];
#pragma unroll
    for (int r = 0; r < 8; ++r) {
        v[r] = *reinterpret_cast<const float4*>(src + r * 256 + lane * 4);
    }

    // --- stages over bits 0,1 (within float4) ---
#pragma unroll
    for (int r = 0; r < 8; ++r) {
        float4 a = v[r];
        float x = a.x + a.y, y = a.x - a.y;   // bit 0: (x,y),(z,w)
        float z = a.z + a.w, w = a.z - a.w;
        a.x = x + z; a.z = x - z;             // bit 1: (x,z),(y,w)
        a.y = y + w; a.w = y - w;
        v[r] = a;
    }

    // --- stages over bits 2..7 (lane bits), xor masks 1..32 ---
#pragma unroll
    for (int m = 1; m <= 32; m <<= 1) {
        const float s = (lane & m) ? -1.0f : 1.0f;
#pragma unroll
        for (int r = 0; r < 8; ++r) {
            float4 a = v[r];
            float px = __shfl_xor(a.x, m, 64);
            float py = __shfl_xor(a.y, m, 64);
            float pz = __shfl_xor(a.z, m, 64);
            float pw = __shfl_xor(a.w, m, 64);
            a.x = px + s * a.x;
            a.y = py + s * a.y;
            a.z = pz + s * a.z;
            a.w = pw + s * a.w;
            v[r] = a;
        }
    }

    // --- stages over bits 8,9,10 (r strides 1,2,4) ---
#pragma unroll
    for (int s = 1; s <= 4; s <<= 1) {
#pragma unroll
        for (int i = 0; i < 8; ++i) {
            if ((i & s) == 0) {
                float4 a = v[i], b = v[i + s];
                v[i].x = a.x + b.x; v[i].y = a.y + b.y;
                v[i].z = a.z + b.z; v[i].w = a.w + b.w;
                v[i + s].x = a.x - b.x; v[i + s].y = a.y - b.y;
                v[i + s].z = a.z - b.z; v[i + s].w = a.w - b.w;
            }
        }
    }

    // --- scale 1/sqrt(2048), CZ sign = -1 iff r bits 2,1 both set (r=6,7) ---
    const float SCALE = 0.022097086912079612f;  // 2^-5.5
#pragma unroll
    for (int r = 0; r < 8; ++r) {
        const float sc = ((r & 6) == 6) ? -SCALE : SCALE;
        float4 a = v[r];
        f32x4 o;
        o.x = a.x * sc; o.y = a.y * sc; o.z = a.z * sc; o.w = a.w * sc;
        __builtin_nontemporal_store(o, reinterpret_cast<f32x4*>(dst + r * 256 + lane * 4));
    }
}

extern "C" void kernel_launch(void* const* d_in, const int* in_sizes, int n_in,
                              void* d_out, int out_size, void* d_ws, size_t ws_size,
                              hipStream_t stream) {
    const float* in = (const float*)d_in[0];
    float* out = (float*)d_out;
    const int batch = in_sizes[0] / N;  // 16384
    const int grid = (batch + ROWS_PER_BLOCK - 1) / ROWS_PER_BLOCK;
    QuantumLikeLayer_kernel<<<grid, 256, 0, stream>>>(in, out, batch);
}

// Round 5
// 44.652 us; speedup vs baseline: 1.1000x; 1.0590x over previous
//
#include <hip/hip_runtime.h>

// QuantumLikeLayer: out[b,:] = CZ_diag * (H^{kron 11} @ x[b,:])
// Fast WHT: 11 radix-2 butterfly stages. CZ_diag[i] = -1 iff bits 10,9 of i
// are both 1. Scale 2^-5.5 folded into the store.
//
// R5: revert R4's sc1 store (L2-bypass races the harness's memset-dirty L2
// lines -> stale zeros read back). Keep R3's nt store (+4%).
// New: cross-lane stages for masks 1,2,8 moved from LDS pipe (ds_swizzle via
// __shfl_xor) to VALU DPP (quad_perm / row_ror:8) -- halves LDS-pipe ops.
// Masks 4,16,32 remain __shfl_xor.

#define N 2048
#define ROWS_PER_BLOCK 4  // 4 waves/block, one row per wave

typedef float f32x4 __attribute__((ext_vector_type(4)));

template <int CTRL>
__device__ __forceinline__ float dpp_perm(float x) {
    return __builtin_bit_cast(
        float, __builtin_amdgcn_update_dpp(0, __builtin_bit_cast(int, x),
                                           CTRL, 0xF, 0xF, true));
}

template <int M>
__device__ __forceinline__ float partner(float x) {
    if constexpr (M == 1)      return dpp_perm<0xB1>(x);   // quad_perm [1,0,3,2]
    else if constexpr (M == 2) return dpp_perm<0x4E>(x);   // quad_perm [2,3,0,1]
    else if constexpr (M == 8) return dpp_perm<0x128>(x);  // row_ror:8 == xor 8
    else                       return __shfl_xor(x, M, 64);
}

template <int M>
__device__ __forceinline__ void bfly_stage(float4* v, int lane) {
    const float s = (lane & M) ? -1.0f : 1.0f;
#pragma unroll
    for (int r = 0; r < 8; ++r) {
        float4 a = v[r];
        float px = partner<M>(a.x);
        float py = partner<M>(a.y);
        float pz = partner<M>(a.z);
        float pw = partner<M>(a.w);
        a.x = px + s * a.x;
        a.y = py + s * a.y;
        a.z = pz + s * a.z;
        a.w = pw + s * a.w;
        v[r] = a;
    }
}

__global__ __launch_bounds__(256) void QuantumLikeLayer_kernel(
    const float* __restrict__ in, float* __restrict__ out, int batch) {
    const int lane = threadIdx.x & 63;
    const int wave = threadIdx.x >> 6;
    const int row = blockIdx.x * ROWS_PER_BLOCK + wave;
    if (row >= batch) return;

    const float* src = in + (size_t)row * N;
    float*       dst = out + (size_t)row * N;

    // Element index i = r*256 + lane*4 + c  (r: bits 8-10, lane: bits 2-7, c: bits 0-1)
    float4 v[8];
#pragma unroll
    for (int r = 0; r < 8; ++r) {
        v[r] = *reinterpret_cast<const float4*>(src + r * 256 + lane * 4);
    }

    // --- stages over bits 0,1 (within float4) ---
#pragma unroll
    for (int r = 0; r < 8; ++r) {
        float4 a = v[r];
        float x = a.x + a.y, y = a.x - a.y;   // bit 0
        float z = a.z + a.w, w = a.z - a.w;
        a.x = x + z; a.z = x - z;             // bit 1
        a.y = y + w; a.w = y - w;
        v[r] = a;
    }

    // --- stages over bits 2..7 (lane bits), xor masks 1..32 ---
    bfly_stage<1>(v, lane);
    bfly_stage<2>(v, lane);
    bfly_stage<4>(v, lane);
    bfly_stage<8>(v, lane);
    bfly_stage<16>(v, lane);
    bfly_stage<32>(v, lane);

    // --- stages over bits 8,9,10 (r strides 1,2,4) ---
#pragma unroll
    for (int s = 1; s <= 4; s <<= 1) {
#pragma unroll
        for (int i = 0; i < 8; ++i) {
            if ((i & s) == 0) {
                float4 a = v[i], b = v[i + s];
                v[i].x = a.x + b.x; v[i].y = a.y + b.y;
                v[i].z = a.z + b.z; v[i].w = a.w + b.w;
                v[i + s].x = a.x - b.x; v[i + s].y = a.y - b.y;
                v[i + s].z = a.z - b.z; v[i + s].w = a.w - b.w;
            }
        }
    }

    // --- scale 1/sqrt(2048), CZ sign = -1 iff r bits 2,1 both set (r=6,7) ---
    const float SCALE = 0.022097086912079612f;  // 2^-5.5
#pragma unroll
    for (int r = 0; r < 8; ++r) {
        const float sc = ((r & 6) == 6) ? -SCALE : SCALE;
        float4 a = v[r];
        f32x4 o;
        o.x = a.x * sc; o.y = a.y * sc; o.z = a.z * sc; o.w = a.w * sc;
        __builtin_nontemporal_store(o, reinterpret_cast<f32x4*>(dst + r * 256 + lane * 4));
    }
}

extern "C" void kernel_launch(void* const* d_in, const int* in_sizes, int n_in,
                              void* d_out, int out_size, void* d_ws, size_t ws_size,
                              hipStream_t stream) {
    const float* in = (const float*)d_in[0];
    float* out = (float*)d_out;
    const int batch = in_sizes[0] / N;  // 16384
    const int grid = (batch + ROWS_PER_BLOCK - 1) / ROWS_PER_BLOCK;
    QuantumLikeLayer_kernel<<<grid, 256, 0, stream>>>(in, out, batch);
}